// Round 3
// baseline (2376.575 us; speedup 1.0000x reference)
//
#include <hip/hip_runtime.h>
#include <math.h>

#define BS_    256
#define FEAT_  2048
#define EMB_   512
#define MEM_   1024
#define VOCAB_ 10000
#define TT_    32
#define NSTEP  31
#define VT_    128
#define NTV_   79      // ceil(10000/128)
#define MROWS_ 7936    // 31*256

typedef unsigned short u16;
typedef __bf16 bf16x8 __attribute__((ext_vector_type(8)));
typedef float  f32x4  __attribute__((ext_vector_type(4)));
typedef u16    u16x8  __attribute__((ext_vector_type(8)));
typedef u16    u16x4  __attribute__((ext_vector_type(4)));
typedef bf16x8 __attribute__((may_alias)) bf16x8_ma;
typedef u16x8  __attribute__((may_alias)) u16x8_ma;
typedef u16x4  __attribute__((may_alias)) u16x4_ma;
typedef float4 __attribute__((may_alias)) float4_ma;

__device__ __forceinline__ u16 f2bf(float f) {
  unsigned u = __float_as_uint(f);
  u += 0x7FFFu + ((u >> 16) & 1u);
  return (u16)(u >> 16);
}

__device__ __forceinline__ void async16(const void* g, void* s) {
  __builtin_amdgcn_global_load_lds((const __attribute__((address_space(1))) void*)g,
                                   (__attribute__((address_space(3))) void*)s, 16, 0, 0);
}

__device__ __forceinline__ float redmax16(float v) {
#pragma unroll
  for (int m = 1; m < 16; m <<= 1) v = fmaxf(v, __shfl_xor(v, m, 64));
  return v;
}
__device__ __forceinline__ float redsum16(float v) {
#pragma unroll
  for (int m = 1; m < 16; m <<= 1) v += __shfl_xor(v, m, 64);
  return v;
}
__device__ __forceinline__ float sigmoidf_(float x) { return 1.0f / (1.0f + __expf(-x)); }

// ---------------------------------------------------------------------------
// fp32 -> bf16 bulk convert (x4 vectorized)
// ---------------------------------------------------------------------------
__global__ __launch_bounds__(256) void cvt_bf16_k(const float* __restrict__ in,
                                                  u16* __restrict__ out, int n4) {
  int i = blockIdx.x * 256 + threadIdx.x;
  if (i >= n4) return;
  float4 v = ((const float4_ma*)in)[i];
  u16x4 o = { f2bf(v.x), f2bf(v.y), f2bf(v.z), f2bf(v.w) };
  *(u16x4_ma*)(out + (size_t)i * 4) = o;
}

// ---------------------------------------------------------------------------
// Gate-permuted weight conversion.  Permuted row r: unit u=r>>2, gate g=r&3,
// source row s = g*1024+u.  One block per permuted row.
// ---------------------------------------------------------------------------
__global__ __launch_bounds__(128) void cvt_permute_k(
    const float* __restrict__ W_ih, const float* __restrict__ W_hh,
    const float* __restrict__ b_ih, const float* __restrict__ b_hh,
    u16* __restrict__ WPih, u16* __restrict__ WPhh, float* __restrict__ biasP) {
  int r = blockIdx.x, tid = threadIdx.x;
  int u = r >> 2, g = r & 3, s = g * 1024 + u;
  {
    float4 v = *(const float4_ma*)(W_ih + (size_t)s * EMB_ + tid * 4);
    u16x4 o = { f2bf(v.x), f2bf(v.y), f2bf(v.z), f2bf(v.w) };
    *(u16x4_ma*)(WPih + (size_t)r * EMB_ + tid * 4) = o;
  }
#pragma unroll
  for (int h = 0; h < 2; ++h) {
    int idx = h * 512 + tid * 4;
    float4 v = *(const float4_ma*)(W_hh + (size_t)s * MEM_ + idx);
    u16x4 o = { f2bf(v.x), f2bf(v.y), f2bf(v.z), f2bf(v.w) };
    *(u16x4_ma*)(WPhh + (size_t)r * MEM_ + idx) = o;
  }
  if (tid == 0) biasP[r] = b_ih[s] + b_hh[s];
}

// ---------------------------------------------------------------------------
// Gather all step embeddings: X_all[t][b][e] = bf16(emb[caption[b][t]][e])
// ---------------------------------------------------------------------------
__global__ __launch_bounds__(256) void gather_x_k(const float* __restrict__ emb,
                                                  const int* __restrict__ caption,
                                                  u16* __restrict__ X) {
  int i = blockIdx.x * 256 + threadIdx.x;
  int e4 = (i & 127) * 4;
  int b  = (i >> 7) & 255;
  int t  = i >> 15;
  int cap = caption[b * TT_ + t];
  float4 v = *(const float4_ma*)(emb + (size_t)cap * EMB_ + e4);
  u16x4 o = { f2bf(v.x), f2bf(v.y), f2bf(v.z), f2bf(v.w) };
  *(u16x4_ma*)(X + ((size_t)(t * 256 + b) * EMB_ + e4)) = o;
}

// ---------------------------------------------------------------------------
// fp32 vector GEMM fallback for init: C = A @ B^T + bias
// ---------------------------------------------------------------------------
__global__ __launch_bounds__(256) void gemm_nt_bias_k(
    const float* __restrict__ A, const float* __restrict__ B,
    const float* __restrict__ bias, float* __restrict__ C, u16* __restrict__ Cb,
    int M, int N, int K) {
  __shared__ float As[16][65];
  __shared__ float Bs[16][65];
  int tid = threadIdx.x;
  int bx = blockIdx.x, by = blockIdx.y;
  int tx = tid & 15, ty = tid >> 4;
  float acc[4][4] = {};
  for (int k0 = 0; k0 < K; k0 += 16) {
#pragma unroll
    for (int i = 0; i < 4; ++i) {
      int idx = tid + i * 256;
      As[idx & 15][idx >> 4] = A[(size_t)(by * 64 + (idx >> 4)) * K + k0 + (idx & 15)];
    }
#pragma unroll
    for (int i = 0; i < 4; ++i) {
      int idx = tid + i * 256;
      Bs[idx & 15][idx >> 4] = B[(size_t)(bx * 64 + (idx >> 4)) * K + k0 + (idx & 15)];
    }
    __syncthreads();
#pragma unroll
    for (int kk = 0; kk < 16; ++kk) {
      float a[4], b[4];
#pragma unroll
      for (int i = 0; i < 4; ++i) a[i] = As[kk][ty * 4 + i];
#pragma unroll
      for (int j = 0; j < 4; ++j) b[j] = Bs[kk][tx * 4 + j];
#pragma unroll
      for (int i = 0; i < 4; ++i)
#pragma unroll
        for (int j = 0; j < 4; ++j) acc[i][j] += a[i] * b[j];
    }
    __syncthreads();
  }
#pragma unroll
  for (int i = 0; i < 4; ++i) {
    int gm = by * 64 + ty * 4 + i;
#pragma unroll
    for (int j = 0; j < 4; ++j) {
      int gn = bx * 64 + tx * 4 + j;
      float v = acc[i][j] + bias[gn];
      if (C)  C[(size_t)gm * N + gn] = v;
      if (Cb) Cb[(size_t)gm * N + gn] = f2bf(v);
    }
  }
}

// ---------------------------------------------------------------------------
// MFMA init GEMM: out = feature(256x2048) @ W(1024x2048)^T + bias
// 64x64 tile, 4 waves, register-prefetch pipeline.  Grid (16, 4).
// ---------------------------------------------------------------------------
__global__ __launch_bounds__(256) void mfma_init_k(
    const u16* __restrict__ A, const u16* __restrict__ Bw,
    const float* __restrict__ bias, u16* __restrict__ outB, float* __restrict__ outF) {
  __shared__ __align__(16) u16 sA[64 * 32];
  __shared__ __align__(16) u16 sB[64 * 32];
  const int tid = threadIdx.x;
  const int m0 = blockIdx.y * 64, n0 = blockIdx.x * 64;
  const int l = tid & 63, wid = tid >> 6;
  const int wm = (wid & 1) * 32, wn = (wid >> 1) * 32;
  const int q = l >> 4, ln = l & 15;
  const int srow = tid >> 2, scol = (tid & 3) * 8;
  const u16* Ar = A + (size_t)(m0 + srow) * FEAT_ + scol;
  const u16* Br = Bw + (size_t)(n0 + srow) * FEAT_ + scol;

  f32x4 acc[2][2];
  const f32x4 z = {0.f, 0.f, 0.f, 0.f};
  acc[0][0] = z; acc[0][1] = z; acc[1][0] = z; acc[1][1] = z;

  u16x8 ra = *(const u16x8_ma*)Ar;
  u16x8 rb = *(const u16x8_ma*)Br;
  for (int it = 0; it < FEAT_ / 32; ++it) {
    *(u16x8_ma*)(sA + srow * 32 + scol) = ra;
    *(u16x8_ma*)(sB + srow * 32 + scol) = rb;
    __syncthreads();
    if (it + 1 < FEAT_ / 32) {
      ra = *(const u16x8_ma*)(Ar + (it + 1) * 32);
      rb = *(const u16x8_ma*)(Br + (it + 1) * 32);
    }
    bf16x8 a0 = *(const bf16x8_ma*)(sA + (wm + ln) * 32 + q * 8);
    bf16x8 a1 = *(const bf16x8_ma*)(sA + (wm + 16 + ln) * 32 + q * 8);
    bf16x8 b0 = *(const bf16x8_ma*)(sB + (wn + ln) * 32 + q * 8);
    bf16x8 b1 = *(const bf16x8_ma*)(sB + (wn + 16 + ln) * 32 + q * 8);
    acc[0][0] = __builtin_amdgcn_mfma_f32_16x16x32_bf16(a0, b0, acc[0][0], 0, 0, 0);
    acc[0][1] = __builtin_amdgcn_mfma_f32_16x16x32_bf16(a0, b1, acc[0][1], 0, 0, 0);
    acc[1][0] = __builtin_amdgcn_mfma_f32_16x16x32_bf16(a1, b0, acc[1][0], 0, 0, 0);
    acc[1][1] = __builtin_amdgcn_mfma_f32_16x16x32_bf16(a1, b1, acc[1][1], 0, 0, 0);
    __syncthreads();
  }
#pragma unroll
  for (int i = 0; i < 2; ++i)
#pragma unroll
    for (int j = 0; j < 2; ++j)
#pragma unroll
      for (int r = 0; r < 4; ++r) {
        int row = m0 + wm + i * 16 + q * 4 + r;
        int col = n0 + wn + j * 16 + ln;
        float v = acc[i][j][r] + bias[col];
        if (outB) outB[(size_t)row * MEM_ + col] = f2bf(v);
        if (outF) outF[(size_t)row * MEM_ + col] = v;
      }
}

// ---------------------------------------------------------------------------
// One fused LSTM step for a 64-row x 16-unit tile (64 permuted gate cols).
// Register-prefetch K-loop (K=1536), gate epilogue through LDS, c in sC.
// ---------------------------------------------------------------------------
__device__ __forceinline__ void lstm_step_body(
    int t, int m0, int nt,
    const u16* __restrict__ Xall, u16* __restrict__ Hall,
    const u16* __restrict__ WPih, const u16* __restrict__ WPhh,
    u16* sA, u16* sB, float* sG, float* sC, float bj0, float bj1) {
  const int tid = threadIdx.x;
  const int l = tid & 63, wid = tid >> 6;
  const int wm = (wid & 1) * 32, wn = (wid >> 1) * 32;
  const int q = l >> 4, ln = l & 15;
  const int srow = tid >> 2, scol = (tid & 3) * 8;

  const u16* Ax = Xall + (size_t)t * BS_ * EMB_ + (size_t)(m0 + srow) * EMB_ + scol;
  const u16* Ah = Hall + (size_t)t * BS_ * MEM_ + (size_t)(m0 + srow) * MEM_ + scol;
  const u16* Bi = WPih + (size_t)(nt * 64 + srow) * EMB_ + scol;
  const u16* Bh = WPhh + (size_t)(nt * 64 + srow) * MEM_ + scol;

  f32x4 acc[2][2];
  const f32x4 z = {0.f, 0.f, 0.f, 0.f};
  acc[0][0] = z; acc[0][1] = z; acc[1][0] = z; acc[1][1] = z;

  u16x8 ra = *(const u16x8_ma*)Ax;
  u16x8 rb = *(const u16x8_ma*)Bi;
  for (int it = 0; it < 48; ++it) {
    *(u16x8_ma*)(sA + srow * 32 + scol) = ra;
    *(u16x8_ma*)(sB + srow * 32 + scol) = rb;
    __syncthreads();
    if (it + 1 < 48) {
      int k0 = (it + 1) * 32;
      if (k0 < EMB_) { ra = *(const u16x8_ma*)(Ax + k0); rb = *(const u16x8_ma*)(Bi + k0); }
      else           { ra = *(const u16x8_ma*)(Ah + k0 - EMB_); rb = *(const u16x8_ma*)(Bh + k0 - EMB_); }
    }
    bf16x8 a0 = *(const bf16x8_ma*)(sA + (wm + ln) * 32 + q * 8);
    bf16x8 a1 = *(const bf16x8_ma*)(sA + (wm + 16 + ln) * 32 + q * 8);
    bf16x8 b0 = *(const bf16x8_ma*)(sB + (wn + ln) * 32 + q * 8);
    bf16x8 b1 = *(const bf16x8_ma*)(sB + (wn + 16 + ln) * 32 + q * 8);
    acc[0][0] = __builtin_amdgcn_mfma_f32_16x16x32_bf16(a0, b0, acc[0][0], 0, 0, 0);
    acc[0][1] = __builtin_amdgcn_mfma_f32_16x16x32_bf16(a0, b1, acc[0][1], 0, 0, 0);
    acc[1][0] = __builtin_amdgcn_mfma_f32_16x16x32_bf16(a1, b0, acc[1][0], 0, 0, 0);
    acc[1][1] = __builtin_amdgcn_mfma_f32_16x16x32_bf16(a1, b1, acc[1][1], 0, 0, 0);
    __syncthreads();
  }

  // gate tile -> LDS (stride 68 keeps 16B alignment, breaks bank aliasing)
#pragma unroll
  for (int i = 0; i < 2; ++i)
#pragma unroll
    for (int j = 0; j < 2; ++j)
#pragma unroll
      for (int r = 0; r < 4; ++r)
        sG[(wm + i * 16 + q * 4 + r) * 68 + wn + j * 16 + ln] =
            acc[i][j][r] + (j ? bj1 : bj0);
  __syncthreads();

  // pointwise: thread -> (row, 4 units)
  {
    const int prow = tid >> 2, u0 = (tid & 3) * 4;
    const float* gRow = sG + prow * 68 + u0 * 4;
    float* cRow = sC + prow * 16 + u0;
    u16x4 hv;
#pragma unroll
    for (int k = 0; k < 4; ++k) {
      float4 g4 = *(const float4_ma*)(gRow + k * 4);   // (i,f,g,o)
      float cv = sigmoidf_(g4.y) * cRow[k] + sigmoidf_(g4.x) * tanhf(g4.z);
      cRow[k] = cv;
      hv[k] = f2bf(sigmoidf_(g4.w) * tanhf(cv));
    }
    *(u16x4_ma*)(Hall + (size_t)(t + 1) * BS_ * MEM_ +
                 (size_t)(m0 + prow) * MEM_ + nt * 16 + u0) = hv;
  }
}

// Device-scope grid barrier: fresh counter per step (zeroed before launch).
__device__ __forceinline__ void grid_bar(unsigned* ctr, int slot) {
  __threadfence();
  __syncthreads();
  if (threadIdx.x == 0) {
    __hip_atomic_fetch_add(ctr + slot, 1u, __ATOMIC_ACQ_REL, __HIP_MEMORY_SCOPE_AGENT);
    while (__hip_atomic_load(ctr + slot, __ATOMIC_ACQUIRE, __HIP_MEMORY_SCOPE_AGENT) < 256u)
      __builtin_amdgcn_s_sleep(2);
  }
  __syncthreads();
  __threadfence();
}

// ---------------------------------------------------------------------------
// Persistent LSTM: 256 blocks (= #CUs), each owns a fixed 64-row x 16-unit
// tile; c-slice lives in LDS across all 31 steps.
// ---------------------------------------------------------------------------
__global__ __launch_bounds__(256) void lstm_persist_k(
    const u16* __restrict__ Xall, u16* __restrict__ Hall,
    const u16* __restrict__ WPih, const u16* __restrict__ WPhh,
    const float* __restrict__ biasP, const float* __restrict__ c0,
    unsigned* __restrict__ ctr) {
  __shared__ __align__(16) u16 sA[64 * 32];
  __shared__ __align__(16) u16 sB[64 * 32];
  __shared__ __align__(16) float sG[64 * 68];
  __shared__ __align__(16) float sC[64 * 16];
  const int b = blockIdx.x;
  const int m0 = (b >> 6) * 64, nt = b & 63;
  const int tid = threadIdx.x;
  {
    int prow = tid >> 2, u0 = (tid & 3) * 4;
    *(float4*)(sC + prow * 16 + u0) =
        *(const float4_ma*)(c0 + (size_t)(m0 + prow) * MEM_ + nt * 16 + u0);
  }
  const int wn = ((tid >> 6) >> 1) * 32, ln = tid & 15;
  const float bj0 = biasP[nt * 64 + wn + ln];
  const float bj1 = biasP[nt * 64 + wn + 16 + ln];
  for (int t = 0; t < NSTEP; ++t) {
    lstm_step_body(t, m0, nt, Xall, Hall, WPih, WPhh, sA, sB, sG, sC, bj0, bj1);
    if (t + 1 < NSTEP) grid_bar(ctr, t);
  }
}

// ---------------------------------------------------------------------------
// MFMA logits GEMM + fused LSE partials (unchanged from round 2).
// ---------------------------------------------------------------------------
template <int CONVB>
__global__ __launch_bounds__(256) void mfma_logits_k(
    const u16* __restrict__ H, const u16* __restrict__ WoutB,
    const float* __restrict__ WoutF, const float* __restrict__ bout,
    const int* __restrict__ caption,
    float* __restrict__ pmax, float* __restrict__ psum, float* __restrict__ tlog) {
  __shared__ __align__(16) char smem[16384];
  u16* sA = (u16*)smem;
  u16* sB = (u16*)(smem + 8192);
  const int tid = threadIdx.x;
  const int n0 = blockIdx.x * VT_;
  const int m0 = blockIdx.y * 128;
  const int l = tid & 63, wid = tid >> 6;
  const int wm = (wid & 1) * 64, wn = (wid >> 1) * 64;
  const int q = l >> 4, ln = l & 15;

  f32x4 acc[4][4];
  const f32x4 z = {0.f, 0.f, 0.f, 0.f};
#pragma unroll
  for (int i = 0; i < 4; ++i)
#pragma unroll
    for (int j = 0; j < 4; ++j) acc[i][j] = z;

  const int srow = tid >> 2;
  const int scol = (tid & 3) * 8;

  int brow[2];
#pragma unroll
  for (int r = 0; r < 2; ++r) {
    int gr = n0 + srow + r * 64;
    brow[r] = (gr > VOCAB_ - 1) ? (VOCAB_ - 1) : gr;
  }

  for (int k0 = 0; k0 < MEM_; k0 += 32) {
#pragma unroll
    for (int r = 0; r < 2; ++r)
      async16(H + (size_t)(m0 + srow + r * 64) * MEM_ + k0 + scol,
              sA + (srow + r * 64) * 32 + scol);
    if (CONVB) {
#pragma unroll
      for (int r = 0; r < 2; ++r) {
        const float* g = WoutF + (size_t)brow[r] * MEM_ + k0 + scol;
        float4 v0 = *(const float4_ma*)g;
        float4 v1 = *(const float4_ma*)(g + 4);
        u16x8 o = { f2bf(v0.x), f2bf(v0.y), f2bf(v0.z), f2bf(v0.w),
                    f2bf(v1.x), f2bf(v1.y), f2bf(v1.z), f2bf(v1.w) };
        *(u16x8_ma*)(sB + (srow + r * 64) * 32 + scol) = o;
      }
    } else {
#pragma unroll
      for (int r = 0; r < 2; ++r)
        async16(WoutB + (size_t)brow[r] * MEM_ + k0 + scol,
                sB + (srow + r * 64) * 32 + scol);
    }
    __syncthreads();
    bf16x8 a[4], b[4];
#pragma unroll
    for (int i = 0; i < 4; ++i) a[i] = *(const bf16x8_ma*)(sA + (wm + i * 16 + ln) * 32 + q * 8);
#pragma unroll
    for (int j = 0; j < 4; ++j) b[j] = *(const bf16x8_ma*)(sB + (wn + j * 16 + ln) * 32 + q * 8);
#pragma unroll
    for (int i = 0; i < 4; ++i)
#pragma unroll
      for (int j = 0; j < 4; ++j)
        acc[i][j] = __builtin_amdgcn_mfma_f32_16x16x32_bf16(a[i], b[j], acc[i][j], 0, 0, 0);
    __syncthreads();
  }

  float* eM = (float*)smem;
  float* eS = eM + 256;
  float* eT = eS + 256;
  const int half = wid >> 1;

  int colj[4]; float bj[4];
#pragma unroll
  for (int j = 0; j < 4; ++j) {
    colj[j] = n0 + wn + j * 16 + ln;
    bj[j] = (colj[j] < VOCAB_) ? bout[colj[j]] : 0.f;
  }
#pragma unroll
  for (int i = 0; i < 4; ++i) {
#pragma unroll
    for (int r = 0; r < 4; ++r) {
      const int rloc = wm + i * 16 + q * 4 + r;
      const int trow = m0 + rloc;
      const int tgt = caption[(trow & 255) * TT_ + (trow >> 8) + 1];
      float v[4];
#pragma unroll
      for (int j = 0; j < 4; ++j)
        v[j] = (colj[j] < VOCAB_) ? (acc[i][j][r] + bj[j]) : -INFINITY;
      float mx = fmaxf(fmaxf(v[0], v[1]), fmaxf(v[2], v[3]));
      mx = redmax16(mx);
      mx = fmaxf(mx, -1e30f);
      float s = 0.f, tv = 0.f;
#pragma unroll
      for (int j = 0; j < 4; ++j) {
        s += __expf(v[j] - mx);
        if (colj[j] == tgt) tv += v[j];
      }
      s = redsum16(s);
      tv = redsum16(tv);
      if (ln == 0) {
        eM[rloc * 2 + half] = mx;
        eS[rloc * 2 + half] = s;
        eT[rloc * 2 + half] = tv;
      }
    }
  }
  __syncthreads();
  if (tid < 128) {
    int trow = m0 + tid;
    float m0v = eM[tid * 2], m1v = eM[tid * 2 + 1];
    float M = fmaxf(m0v, m1v);
    float S = eS[tid * 2] * __expf(m0v - M) + eS[tid * 2 + 1] * __expf(m1v - M);
    pmax[(size_t)trow * NTV_ + blockIdx.x] = M;
    psum[(size_t)trow * NTV_ + blockIdx.x] = S;
    int tgt = caption[(trow & 255) * TT_ + (trow >> 8) + 1];
    if (tgt >= n0 && tgt < n0 + VT_) tlog[trow] = eT[tid * 2] + eT[tid * 2 + 1];
  }
}

// ---------------------------------------------------------------------------
__global__ __launch_bounds__(256) void combine_k(
    const float* __restrict__ pmax, const float* __restrict__ psum,
    const float* __restrict__ tlog, const int* __restrict__ caption,
    float* __restrict__ accum) {
  int r = blockIdx.x * 256 + threadIdx.x;
  if (r >= MROWS_) return;
  const float* pm = pmax + (size_t)r * NTV_;
  const float* ps = psum + (size_t)r * NTV_;
  float m = -INFINITY;
  for (int j = 0; j < NTV_; ++j) m = fmaxf(m, pm[j]);
  float s = 0.f;
  for (int j = 0; j < NTV_; ++j) s += ps[j] * __expf(pm[j] - m);
  float nll = m + __logf(s) - tlog[r];
  int tgt = caption[(r & 255) * TT_ + (r >> 8) + 1];
  if (tgt != 0) {
    atomicAdd(&accum[0], nll);
    atomicAdd(&accum[1], 1.f);
  }
}

__global__ void zero_words_k(unsigned* buf) {
  buf[threadIdx.x] = 0u;   // 64 words: accum[2] + barrier counters
}

__global__ void finalize_k(const float* __restrict__ accum, float* __restrict__ out) {
  out[0] = accum[0] / fmaxf(accum[1], 1.0f);
}

// ---------------------------------------------------------------------------
extern "C" void kernel_launch(void* const* d_in, const int* in_sizes, int n_in,
                              void* d_out, int out_size, void* d_ws, size_t ws_size,
                              hipStream_t stream) {
  (void)in_sizes; (void)n_in; (void)out_size;
  const float* feature  = (const float*)d_in[0];
  const int*   caption  = (const int*)d_in[1];
  const float* W_init_h = (const float*)d_in[3];
  const float* b_init_h = (const float*)d_in[4];
  const float* W_init_c = (const float*)d_in[5];
  const float* b_init_c = (const float*)d_in[6];
  const float* emb      = (const float*)d_in[7];
  const float* W_ih     = (const float*)d_in[8];
  const float* b_ih     = (const float*)d_in[9];
  const float* W_hh     = (const float*)d_in[10];
  const float* b_hh     = (const float*)d_in[11];
  const float* W_out    = (const float*)d_in[12];
  const float* b_out    = (const float*)d_in[13];
  float* out = (float*)d_out;

  char* p = (char*)d_ws;
  u16* WPih = (u16*)p;       p += (size_t)4096 * 512 * 2;
  u16* WPhh = (u16*)p;       p += (size_t)4096 * 1024 * 2;
  float* biasP = (float*)p;  p += (size_t)4096 * 4;
  u16* Xall = (u16*)p;       p += (size_t)NSTEP * 256 * 512 * 2;
  u16* Hall = (u16*)p;       p += (size_t)32 * 256 * 1024 * 2;
  float* c0 = (float*)p;     p += (size_t)256 * 1024 * 4;
  float* pmax = (float*)p;   p += (size_t)MROWS_ * NTV_ * 4;
  float* psum = (float*)p;   p += (size_t)MROWS_ * NTV_ * 4;
  float* tlog = (float*)p;   p += (size_t)MROWS_ * 4;
  unsigned* syncbuf = (unsigned*)p; p += 256;
  u16* WoutB = (u16*)p;      p += (size_t)VOCAB_ * 1024 * 2;
  size_t woutEnd = (size_t)(p - (char*)d_ws);
  u16* featB = (u16*)p;      p += (size_t)256 * 2048 * 2;
  u16* WinitHB = (u16*)p;    p += (size_t)1024 * 2048 * 2;
  u16* WinitCB = (u16*)p;    p += (size_t)1024 * 2048 * 2;
  size_t initEnd = (size_t)(p - (char*)d_ws);

  bool haveWoutB = (ws_size >= woutEnd);
  bool haveInitB = (ws_size >= initEnd);

  float* accum = (float*)syncbuf;         // [0..1]
  unsigned* ctr = syncbuf + 2;            // barrier counters [31]

  dim3 blk(256);
  zero_words_k<<<1, 64, 0, stream>>>(syncbuf);
  cvt_permute_k<<<4096, 128, 0, stream>>>(W_ih, W_hh, b_ih, b_hh, WPih, WPhh, biasP);
  gather_x_k<<<3968, blk, 0, stream>>>(emb, caption, Xall);
  if (haveWoutB) cvt_bf16_k<<<10000, blk, 0, stream>>>(W_out, WoutB, 2560000);

  if (haveInitB) {
    cvt_bf16_k<<<512, blk, 0, stream>>>(feature, featB, 131072);
    cvt_bf16_k<<<2048, blk, 0, stream>>>(W_init_h, WinitHB, 524288);
    cvt_bf16_k<<<2048, blk, 0, stream>>>(W_init_c, WinitCB, 524288);
    dim3 gi(16, 4);
    mfma_init_k<<<gi, blk, 0, stream>>>(featB, WinitHB, b_init_h, Hall, nullptr);
    mfma_init_k<<<gi, blk, 0, stream>>>(featB, WinitCB, b_init_c, nullptr, c0);
  } else {
    dim3 gi(16, 4);
    gemm_nt_bias_k<<<gi, blk, 0, stream>>>(feature, W_init_h, b_init_h, nullptr, Hall,
                                           BS_, MEM_, FEAT_);
    gemm_nt_bias_k<<<gi, blk, 0, stream>>>(feature, W_init_c, b_init_c, c0, nullptr,
                                           BS_, MEM_, FEAT_);
  }

  lstm_persist_k<<<256, blk, 0, stream>>>(Xall, Hall, WPih, WPhh, biasP, c0, ctr);

  dim3 gp(NTV_, MROWS_ / 128);
  if (haveWoutB)
    mfma_logits_k<0><<<gp, blk, 0, stream>>>(Hall + (size_t)BS_ * MEM_, WoutB, W_out,
                                             b_out, caption, pmax, psum, tlog);
  else
    mfma_logits_k<1><<<gp, blk, 0, stream>>>(Hall + (size_t)BS_ * MEM_, WoutB, W_out,
                                             b_out, caption, pmax, psum, tlog);

  combine_k<<<31, blk, 0, stream>>>(pmax, psum, tlog, caption, accum);
  finalize_k<<<1, 1, 0, stream>>>(accum, out);
}

// Round 4
// 1053.855 us; speedup vs baseline: 2.2551x; 2.2551x over previous
//
#include <hip/hip_runtime.h>
#include <math.h>

#define BS_    256
#define FEAT_  2048
#define EMB_   512
#define MEM_   1024
#define VOCAB_ 10000
#define TT_    32
#define NSTEP  31
#define VT_    128
#define NTV_   79      // ceil(10000/128)
#define MROWS_ 7936    // 31*256
#define PAD_   40      // LDS row stride in bf16 elems: 80B = 16B-aligned, 2-way banks

typedef unsigned short u16;
typedef __bf16 bf16x8 __attribute__((ext_vector_type(8)));
typedef float  f32x4  __attribute__((ext_vector_type(4)));
typedef u16    u16x8  __attribute__((ext_vector_type(8)));
typedef u16    u16x4  __attribute__((ext_vector_type(4)));
typedef bf16x8 __attribute__((may_alias)) bf16x8_ma;
typedef u16x8  __attribute__((may_alias)) u16x8_ma;
typedef u16x4  __attribute__((may_alias)) u16x4_ma;
typedef float4 __attribute__((may_alias)) float4_ma;

__device__ __forceinline__ u16 f2bf(float f) {
  unsigned u = __float_as_uint(f);
  u += 0x7FFFu + ((u >> 16) & 1u);
  return (u16)(u >> 16);
}

__device__ __forceinline__ void async16(const void* g, void* s) {
  __builtin_amdgcn_global_load_lds((const __attribute__((address_space(1))) void*)g,
                                   (__attribute__((address_space(3))) void*)s, 16, 0, 0);
}

__device__ __forceinline__ float redsum16(float v) {
#pragma unroll
  for (int m = 1; m < 16; m <<= 1) v += __shfl_xor(v, m, 64);
  return v;
}
__device__ __forceinline__ float sigmoidf_(float x) { return 1.0f / (1.0f + __expf(-x)); }

// ---------------------------------------------------------------------------
// fp32 -> bf16 bulk convert
// ---------------------------------------------------------------------------
__global__ __launch_bounds__(256) void cvt_bf16_k(const float* __restrict__ in,
                                                  u16* __restrict__ out, int n4) {
  int i = blockIdx.x * 256 + threadIdx.x;
  if (i >= n4) return;
  float4 v = ((const float4_ma*)in)[i];
  u16x4 o = { f2bf(v.x), f2bf(v.y), f2bf(v.z), f2bf(v.w) };
  *(u16x4_ma*)(out + (size_t)i * 4) = o;
}

// ---------------------------------------------------------------------------
// Gate-permuted weight conversion: permuted row r -> source row (r&3)*1024+(r>>2)
// ---------------------------------------------------------------------------
__global__ __launch_bounds__(128) void cvt_permute_k(
    const float* __restrict__ W_ih, const float* __restrict__ W_hh,
    const float* __restrict__ b_ih, const float* __restrict__ b_hh,
    u16* __restrict__ WPih, u16* __restrict__ WPhh, float* __restrict__ biasP) {
  int r = blockIdx.x, tid = threadIdx.x;
  int u = r >> 2, g = r & 3, s = g * 1024 + u;
  {
    float4 v = *(const float4_ma*)(W_ih + (size_t)s * EMB_ + tid * 4);
    u16x4 o = { f2bf(v.x), f2bf(v.y), f2bf(v.z), f2bf(v.w) };
    *(u16x4_ma*)(WPih + (size_t)r * EMB_ + tid * 4) = o;
  }
#pragma unroll
  for (int h = 0; h < 2; ++h) {
    int idx = h * 512 + tid * 4;
    float4 v = *(const float4_ma*)(W_hh + (size_t)s * MEM_ + idx);
    u16x4 o = { f2bf(v.x), f2bf(v.y), f2bf(v.z), f2bf(v.w) };
    *(u16x4_ma*)(WPhh + (size_t)r * MEM_ + idx) = o;
  }
  if (tid == 0) biasP[r] = b_ih[s] + b_hh[s];
}

// ---------------------------------------------------------------------------
// Gather all step embeddings to bf16
// ---------------------------------------------------------------------------
__global__ __launch_bounds__(256) void gather_x_k(const float* __restrict__ emb,
                                                  const int* __restrict__ caption,
                                                  u16* __restrict__ X) {
  int i = blockIdx.x * 256 + threadIdx.x;
  int e4 = (i & 127) * 4;
  int b  = (i >> 7) & 255;
  int t  = i >> 15;
  int cap = caption[b * TT_ + t];
  float4 v = *(const float4_ma*)(emb + (size_t)cap * EMB_ + e4);
  u16x4 o = { f2bf(v.x), f2bf(v.y), f2bf(v.z), f2bf(v.w) };
  *(u16x4_ma*)(X + ((size_t)(t * 256 + b) * EMB_ + e4)) = o;
}

// ---------------------------------------------------------------------------
// fp32 vector GEMM fallback for init
// ---------------------------------------------------------------------------
__global__ __launch_bounds__(256) void gemm_nt_bias_k(
    const float* __restrict__ A, const float* __restrict__ B,
    const float* __restrict__ bias, float* __restrict__ C, u16* __restrict__ Cb,
    int M, int N, int K) {
  __shared__ float As[16][65];
  __shared__ float Bs[16][65];
  int tid = threadIdx.x;
  int bx = blockIdx.x, by = blockIdx.y;
  int tx = tid & 15, ty = tid >> 4;
  float acc[4][4] = {};
  for (int k0 = 0; k0 < K; k0 += 16) {
#pragma unroll
    for (int i = 0; i < 4; ++i) {
      int idx = tid + i * 256;
      As[idx & 15][idx >> 4] = A[(size_t)(by * 64 + (idx >> 4)) * K + k0 + (idx & 15)];
    }
#pragma unroll
    for (int i = 0; i < 4; ++i) {
      int idx = tid + i * 256;
      Bs[idx & 15][idx >> 4] = B[(size_t)(bx * 64 + (idx >> 4)) * K + k0 + (idx & 15)];
    }
    __syncthreads();
#pragma unroll
    for (int kk = 0; kk < 16; ++kk) {
      float a[4], b[4];
#pragma unroll
      for (int i = 0; i < 4; ++i) a[i] = As[kk][ty * 4 + i];
#pragma unroll
      for (int j = 0; j < 4; ++j) b[j] = Bs[kk][tx * 4 + j];
#pragma unroll
      for (int i = 0; i < 4; ++i)
#pragma unroll
        for (int j = 0; j < 4; ++j) acc[i][j] += a[i] * b[j];
    }
    __syncthreads();
  }
#pragma unroll
  for (int i = 0; i < 4; ++i) {
    int gm = by * 64 + ty * 4 + i;
#pragma unroll
    for (int j = 0; j < 4; ++j) {
      int gn = bx * 64 + tx * 4 + j;
      float v = acc[i][j] + bias[gn];
      if (C)  C[(size_t)gm * N + gn] = v;
      if (Cb) Cb[(size_t)gm * N + gn] = f2bf(v);
    }
  }
}

// ---------------------------------------------------------------------------
// MFMA init GEMM: out = feature(256x2048) @ W(1024x2048)^T + bias.  Grid (16,4).
// ---------------------------------------------------------------------------
__global__ __launch_bounds__(256) void mfma_init_k(
    const u16* __restrict__ A, const u16* __restrict__ Bw,
    const float* __restrict__ bias, u16* __restrict__ outB, float* __restrict__ outF) {
  __shared__ __align__(16) u16 sA[2][64 * PAD_];
  __shared__ __align__(16) u16 sB[2][64 * PAD_];
  const int tid = threadIdx.x;
  const int m0 = blockIdx.y * 64, n0 = blockIdx.x * 64;
  const int l = tid & 63, wid = tid >> 6;
  const int wm = (wid & 1) * 32, wn = (wid >> 1) * 32;
  const int q = l >> 4, ln = l & 15;
  const int srow = tid >> 2, scol = (tid & 3) * 8;
  const u16* Ar = A + (size_t)(m0 + srow) * FEAT_ + scol;
  const u16* Br = Bw + (size_t)(n0 + srow) * FEAT_ + scol;

  f32x4 acc[2][2];
  const f32x4 z = {0.f, 0.f, 0.f, 0.f};
  acc[0][0] = z; acc[0][1] = z; acc[1][0] = z; acc[1][1] = z;

  u16x8 ra = *(const u16x8_ma*)Ar;
  u16x8 rb = *(const u16x8_ma*)Br;
  int p = 0;
  for (int it = 0; it < FEAT_ / 32; ++it) {
    *(u16x8_ma*)(sA[p] + srow * PAD_ + scol) = ra;
    *(u16x8_ma*)(sB[p] + srow * PAD_ + scol) = rb;
    __syncthreads();
    if (it + 1 < FEAT_ / 32) {
      ra = *(const u16x8_ma*)(Ar + (it + 1) * 32);
      rb = *(const u16x8_ma*)(Br + (it + 1) * 32);
    }
    bf16x8 a0 = *(const bf16x8_ma*)(sA[p] + (wm + ln) * PAD_ + q * 8);
    bf16x8 a1 = *(const bf16x8_ma*)(sA[p] + (wm + 16 + ln) * PAD_ + q * 8);
    bf16x8 b0 = *(const bf16x8_ma*)(sB[p] + (wn + ln) * PAD_ + q * 8);
    bf16x8 b1 = *(const bf16x8_ma*)(sB[p] + (wn + 16 + ln) * PAD_ + q * 8);
    acc[0][0] = __builtin_amdgcn_mfma_f32_16x16x32_bf16(a0, b0, acc[0][0], 0, 0, 0);
    acc[0][1] = __builtin_amdgcn_mfma_f32_16x16x32_bf16(a0, b1, acc[0][1], 0, 0, 0);
    acc[1][0] = __builtin_amdgcn_mfma_f32_16x16x32_bf16(a1, b0, acc[1][0], 0, 0, 0);
    acc[1][1] = __builtin_amdgcn_mfma_f32_16x16x32_bf16(a1, b1, acc[1][1], 0, 0, 0);
    p ^= 1;
  }
#pragma unroll
  for (int i = 0; i < 2; ++i)
#pragma unroll
    for (int j = 0; j < 2; ++j)
#pragma unroll
      for (int r = 0; r < 4; ++r) {
        int row = m0 + wm + i * 16 + q * 4 + r;
        int col = n0 + wn + j * 16 + ln;
        float v = acc[i][j][r] + bias[col];
        if (outB) outB[(size_t)row * MEM_ + col] = f2bf(v);
        if (outF) outF[(size_t)row * MEM_ + col] = v;
      }
}

// ---------------------------------------------------------------------------
// Fused LSTM step: 256 blocks x 256 thr.  Block -> 64 rows x 64 permuted cols
// (16 units).  Double-buffered LDS + register prefetch, fused pointwise.
// ---------------------------------------------------------------------------
__global__ __launch_bounds__(256) void lstm_step_k(
    const u16* __restrict__ Xt, const u16* __restrict__ Hin,
    u16* __restrict__ Hout,
    const u16* __restrict__ WPih, const u16* __restrict__ WPhh,
    const float* __restrict__ biasP, float* __restrict__ c) {
  __shared__ __align__(16) u16 sA[2][64 * PAD_];
  __shared__ __align__(16) u16 sB[2][64 * PAD_];
  __shared__ __align__(16) float sG[64 * 68];
  const int tid = threadIdx.x;
  const int b = blockIdx.x;
  const int m0 = (b >> 6) * 64, nt = b & 63;
  const int l = tid & 63, wid = tid >> 6;
  const int wm = (wid & 1) * 32, wn = (wid >> 1) * 32;
  const int q = l >> 4, ln = l & 15;
  const int srow = tid >> 2, scol = (tid & 3) * 8;

  const u16* Ax = Xt + (size_t)(m0 + srow) * EMB_ + scol;
  const u16* Ah = Hin + (size_t)(m0 + srow) * MEM_ + scol;
  const u16* Bi = WPih + (size_t)(nt * 64 + srow) * EMB_ + scol;
  const u16* Bh = WPhh + (size_t)(nt * 64 + srow) * MEM_ + scol;

  const float bj0 = biasP[nt * 64 + wn + ln];
  const float bj1 = biasP[nt * 64 + wn + 16 + ln];

  f32x4 acc[2][2];
  const f32x4 z = {0.f, 0.f, 0.f, 0.f};
  acc[0][0] = z; acc[0][1] = z; acc[1][0] = z; acc[1][1] = z;

  u16x8 ra = *(const u16x8_ma*)Ax;
  u16x8 rb = *(const u16x8_ma*)Bi;
  int p = 0;
  for (int it = 0; it < 48; ++it) {
    *(u16x8_ma*)(sA[p] + srow * PAD_ + scol) = ra;
    *(u16x8_ma*)(sB[p] + srow * PAD_ + scol) = rb;
    __syncthreads();
    if (it + 1 < 48) {
      int k0 = (it + 1) * 32;
      if (k0 < EMB_) { ra = *(const u16x8_ma*)(Ax + k0); rb = *(const u16x8_ma*)(Bi + k0); }
      else { ra = *(const u16x8_ma*)(Ah + (k0 - EMB_)); rb = *(const u16x8_ma*)(Bh + (k0 - EMB_)); }
    }
    bf16x8 a0 = *(const bf16x8_ma*)(sA[p] + (wm + ln) * PAD_ + q * 8);
    bf16x8 a1 = *(const bf16x8_ma*)(sA[p] + (wm + 16 + ln) * PAD_ + q * 8);
    bf16x8 b0 = *(const bf16x8_ma*)(sB[p] + (wn + ln) * PAD_ + q * 8);
    bf16x8 b1 = *(const bf16x8_ma*)(sB[p] + (wn + 16 + ln) * PAD_ + q * 8);
    acc[0][0] = __builtin_amdgcn_mfma_f32_16x16x32_bf16(a0, b0, acc[0][0], 0, 0, 0);
    acc[0][1] = __builtin_amdgcn_mfma_f32_16x16x32_bf16(a0, b1, acc[0][1], 0, 0, 0);
    acc[1][0] = __builtin_amdgcn_mfma_f32_16x16x32_bf16(a1, b0, acc[1][0], 0, 0, 0);
    acc[1][1] = __builtin_amdgcn_mfma_f32_16x16x32_bf16(a1, b1, acc[1][1], 0, 0, 0);
    p ^= 1;
  }

  // gate tile -> sG (separate LDS region; no hazard with staging buffers)
#pragma unroll
  for (int i = 0; i < 2; ++i)
#pragma unroll
    for (int j = 0; j < 2; ++j)
#pragma unroll
      for (int r = 0; r < 4; ++r)
        sG[(wm + i * 16 + q * 4 + r) * 68 + wn + j * 16 + ln] =
            acc[i][j][r] + (j ? bj1 : bj0);
  __syncthreads();

  // pointwise: thread -> (row, 4 units); c in global fp32
  {
    const int prow = tid >> 2, u0 = (tid & 3) * 4;
    const float* gRow = sG + prow * 68 + u0 * 4;
    float* cp = c + (size_t)(m0 + prow) * MEM_ + nt * 16 + u0;
    float4 cv = *(const float4_ma*)cp;
    float cva[4] = {cv.x, cv.y, cv.z, cv.w};
    u16x4 hv;
    float4 cn;
    float cna[4];
#pragma unroll
    for (int k = 0; k < 4; ++k) {
      float4 g4 = *(const float4_ma*)(gRow + k * 4);   // (i,f,g,o)
      float cvn = sigmoidf_(g4.y) * cva[k] + sigmoidf_(g4.x) * tanhf(g4.z);
      cna[k] = cvn;
      hv[k] = f2bf(sigmoidf_(g4.w) * tanhf(cvn));
    }
    cn.x = cna[0]; cn.y = cna[1]; cn.z = cna[2]; cn.w = cna[3];
    *(float4_ma*)cp = cn;
    *(u16x4_ma*)(Hout + (size_t)(m0 + prow) * MEM_ + nt * 16 + u0) = hv;
  }
}

// ---------------------------------------------------------------------------
// MFMA logits GEMM + fused sum-exp partials (no max-shift: |logit| <= ~18).
// Tile 128x128, 4 waves, double-buffered padded LDS, register prefetch.
// 1D grid, vt-major: vt = bid/62 so a B-tile's 62 row-blocks are adjacent.
// ---------------------------------------------------------------------------
__global__ __launch_bounds__(256) void mfma_logits_k(
    const u16* __restrict__ H, const u16* __restrict__ WoutB,
    const float* __restrict__ bout, const int* __restrict__ caption,
    float* __restrict__ psum, float* __restrict__ tlog) {
  __shared__ __align__(16) u16 sA[2][128 * PAD_];
  __shared__ __align__(16) u16 sB[2][128 * PAD_];
  const int tid = threadIdx.x;
  const int bid = blockIdx.x;
  const int vt = bid / 62, mt = bid - vt * 62;
  const int n0 = vt * VT_, m0 = mt * 128;
  const int l = tid & 63, wid = tid >> 6;
  const int wm = (wid & 1) * 64, wn = (wid >> 1) * 64;
  const int q = l >> 4, ln = l & 15;

  f32x4 acc[4][4];
  const f32x4 z = {0.f, 0.f, 0.f, 0.f};
#pragma unroll
  for (int i = 0; i < 4; ++i)
#pragma unroll
    for (int j = 0; j < 4; ++j) acc[i][j] = z;

  // staging: 2 chunks each for A and B per thread
  int arow[2], acol[2], brow[2];
#pragma unroll
  for (int r = 0; r < 2; ++r) {
    int idx = tid + r * 256;
    arow[r] = idx >> 2;
    acol[r] = (idx & 3) * 8;
    int gr = n0 + arow[r];
    brow[r] = (gr > VOCAB_ - 1) ? (VOCAB_ - 1) : gr;
  }

  u16x8 ra[2], rb[2];
#pragma unroll
  for (int r = 0; r < 2; ++r) {
    ra[r] = *(const u16x8_ma*)(H + (size_t)(m0 + arow[r]) * MEM_ + acol[r]);
    rb[r] = *(const u16x8_ma*)(WoutB + (size_t)brow[r] * MEM_ + acol[r]);
  }
  int p = 0;
  for (int it = 0; it < 32; ++it) {
#pragma unroll
    for (int r = 0; r < 2; ++r) {
      *(u16x8_ma*)(sA[p] + arow[r] * PAD_ + acol[r]) = ra[r];
      *(u16x8_ma*)(sB[p] + arow[r] * PAD_ + acol[r]) = rb[r];
    }
    __syncthreads();
    if (it + 1 < 32) {
      int k0 = (it + 1) * 32;
#pragma unroll
      for (int r = 0; r < 2; ++r) {
        ra[r] = *(const u16x8_ma*)(H + (size_t)(m0 + arow[r]) * MEM_ + k0 + acol[r]);
        rb[r] = *(const u16x8_ma*)(WoutB + (size_t)brow[r] * MEM_ + k0 + acol[r]);
      }
    }
    bf16x8 a[4], b[4];
#pragma unroll
    for (int i = 0; i < 4; ++i) a[i] = *(const bf16x8_ma*)(sA[p] + (wm + i * 16 + ln) * PAD_ + q * 8);
#pragma unroll
    for (int j = 0; j < 4; ++j) b[j] = *(const bf16x8_ma*)(sB[p] + (wn + j * 16 + ln) * PAD_ + q * 8);
#pragma unroll
    for (int i = 0; i < 4; ++i)
#pragma unroll
      for (int j = 0; j < 4; ++j)
        acc[i][j] = __builtin_amdgcn_mfma_f32_16x16x32_bf16(a[i], b[j], acc[i][j], 0, 0, 0);
    __syncthreads();
    p ^= 1;
  }

  // ---- fused sum-exp epilogue (reuse sA as float scratch) ----
  float* eS = (float*)sA;          // [128][2]
  float* eT = eS + 256;
  const int half = wid >> 1;

  int colj[4]; float bj[4];
#pragma unroll
  for (int j = 0; j < 4; ++j) {
    colj[j] = n0 + wn + j * 16 + ln;
    bj[j] = (colj[j] < VOCAB_) ? bout[colj[j]] : 0.f;
  }
#pragma unroll
  for (int i = 0; i < 4; ++i) {
#pragma unroll
    for (int r = 0; r < 4; ++r) {
      const int rloc = wm + i * 16 + q * 4 + r;
      const int trow = m0 + rloc;
      const int tgt = caption[(trow & 255) * TT_ + (trow >> 8) + 1];
      float s = 0.f, tv = 0.f;
#pragma unroll
      for (int j = 0; j < 4; ++j) {
        if (colj[j] < VOCAB_) {
          float v = acc[i][j][r] + bj[j];
          s += __expf(v);
          if (colj[j] == tgt) tv += v;
        }
      }
      s = redsum16(s);
      tv = redsum16(tv);
      if (ln == 0) {
        eS[rloc * 2 + half] = s;
        eT[rloc * 2 + half] = tv;
      }
    }
  }
  __syncthreads();
  if (tid < 128) {
    int trow = m0 + tid;
    psum[(size_t)trow * NTV_ + vt] = eS[tid * 2] + eS[tid * 2 + 1];
    int tgt = caption[(trow & 255) * TT_ + (trow >> 8) + 1];
    if (tgt >= n0 && tgt < n0 + VT_) tlog[trow] = eT[tid * 2] + eT[tid * 2 + 1];
  }
}

// ---------------------------------------------------------------------------
// Fallback logits (fp32 W_out staged inline), async16 path — only if ws small.
// ---------------------------------------------------------------------------
__global__ __launch_bounds__(256) void mfma_logits_conv_k(
    const u16* __restrict__ H, const float* __restrict__ WoutF,
    const float* __restrict__ bout, const int* __restrict__ caption,
    float* __restrict__ psum, float* __restrict__ tlog) {
  __shared__ __align__(16) char smem[16384];
  u16* sA = (u16*)smem;
  u16* sB = (u16*)(smem + 8192);
  const int tid = threadIdx.x;
  const int bid = blockIdx.x;
  const int vt = bid / 62, mt = bid - vt * 62;
  const int n0 = vt * VT_, m0 = mt * 128;
  const int l = tid & 63, wid = tid >> 6;
  const int wm = (wid & 1) * 64, wn = (wid >> 1) * 64;
  const int q = l >> 4, ln = l & 15;
  f32x4 acc[4][4];
  const f32x4 z = {0.f, 0.f, 0.f, 0.f};
#pragma unroll
  for (int i = 0; i < 4; ++i)
#pragma unroll
    for (int j = 0; j < 4; ++j) acc[i][j] = z;
  const int srow = tid >> 2, scol = (tid & 3) * 8;
  int brow[2];
#pragma unroll
  for (int r = 0; r < 2; ++r) {
    int gr = n0 + srow + r * 64;
    brow[r] = (gr > VOCAB_ - 1) ? (VOCAB_ - 1) : gr;
  }
  for (int k0 = 0; k0 < MEM_; k0 += 32) {
#pragma unroll
    for (int r = 0; r < 2; ++r)
      async16(H + (size_t)(m0 + srow + r * 64) * MEM_ + k0 + scol,
              sA + (srow + r * 64) * 32 + scol);
#pragma unroll
    for (int r = 0; r < 2; ++r) {
      const float* g = WoutF + (size_t)brow[r] * MEM_ + k0 + scol;
      float4 v0 = *(const float4_ma*)g;
      float4 v1 = *(const float4_ma*)(g + 4);
      u16x8 o = { f2bf(v0.x), f2bf(v0.y), f2bf(v0.z), f2bf(v0.w),
                  f2bf(v1.x), f2bf(v1.y), f2bf(v1.z), f2bf(v1.w) };
      *(u16x8_ma*)(sB + (srow + r * 64) * 32 + scol) = o;
    }
    __syncthreads();
    bf16x8 a[4], b[4];
#pragma unroll
    for (int i = 0; i < 4; ++i) a[i] = *(const bf16x8_ma*)(sA + (wm + i * 16 + ln) * 32 + q * 8);
#pragma unroll
    for (int j = 0; j < 4; ++j) b[j] = *(const bf16x8_ma*)(sB + (wn + j * 16 + ln) * 32 + q * 8);
#pragma unroll
    for (int i = 0; i < 4; ++i)
#pragma unroll
      for (int j = 0; j < 4; ++j)
        acc[i][j] = __builtin_amdgcn_mfma_f32_16x16x32_bf16(a[i], b[j], acc[i][j], 0, 0, 0);
    __syncthreads();
  }
  float* eS = (float*)smem;
  float* eT = eS + 256;
  const int half = wid >> 1;
  int colj[4]; float bj[4];
#pragma unroll
  for (int j = 0; j < 4; ++j) {
    colj[j] = n0 + wn + j * 16 + ln;
    bj[j] = (colj[j] < VOCAB_) ? bout[colj[j]] : 0.f;
  }
#pragma unroll
  for (int i = 0; i < 4; ++i) {
#pragma unroll
    for (int r = 0; r < 4; ++r) {
      const int rloc = wm + i * 16 + q * 4 + r;
      const int trow = m0 + rloc;
      const int tgt = caption[(trow & 255) * TT_ + (trow >> 8) + 1];
      float s = 0.f, tv = 0.f;
#pragma unroll
      for (int j = 0; j < 4; ++j) {
        if (colj[j] < VOCAB_) {
          float v = acc[i][j][r] + bj[j];
          s += __expf(v);
          if (colj[j] == tgt) tv += v;
        }
      }
      s = redsum16(s);
      tv = redsum16(tv);
      if (ln == 0) { eS[rloc * 2 + half] = s; eT[rloc * 2 + half] = tv; }
    }
  }
  __syncthreads();
  if (tid < 128) {
    int trow = m0 + tid;
    psum[(size_t)trow * NTV_ + vt] = eS[tid * 2] + eS[tid * 2 + 1];
    int tgt = caption[(trow & 255) * TT_ + (trow >> 8) + 1];
    if (tgt >= n0 && tgt < n0 + VT_) tlog[trow] = eT[tid * 2] + eT[tid * 2 + 1];
  }
}

// ---------------------------------------------------------------------------
__global__ __launch_bounds__(256) void combine_k(
    const float* __restrict__ psum, const float* __restrict__ tlog,
    const int* __restrict__ caption, float* __restrict__ accum) {
  int r = blockIdx.x * 256 + threadIdx.x;
  if (r >= MROWS_) return;
  const float* ps = psum + (size_t)r * NTV_;
  float s = 0.f;
  for (int j = 0; j < NTV_; ++j) s += ps[j];
  float nll = __logf(s) - tlog[r];
  int tgt = caption[(r & 255) * TT_ + (r >> 8) + 1];
  if (tgt != 0) {
    atomicAdd(&accum[0], nll);
    atomicAdd(&accum[1], 1.f);
  }
}

__global__ void zero_words_k(unsigned* buf) {
  buf[threadIdx.x] = 0u;
}

__global__ void finalize_k(const float* __restrict__ accum, float* __restrict__ out) {
  out[0] = accum[0] / fmaxf(accum[1], 1.0f);
}

// ---------------------------------------------------------------------------
extern "C" void kernel_launch(void* const* d_in, const int* in_sizes, int n_in,
                              void* d_out, int out_size, void* d_ws, size_t ws_size,
                              hipStream_t stream) {
  (void)in_sizes; (void)n_in; (void)out_size;
  const float* feature  = (const float*)d_in[0];
  const int*   caption  = (const int*)d_in[1];
  const float* W_init_h = (const float*)d_in[3];
  const float* b_init_h = (const float*)d_in[4];
  const float* W_init_c = (const float*)d_in[5];
  const float* b_init_c = (const float*)d_in[6];
  const float* emb      = (const float*)d_in[7];
  const float* W_ih     = (const float*)d_in[8];
  const float* b_ih     = (const float*)d_in[9];
  const float* W_hh     = (const float*)d_in[10];
  const float* b_hh     = (const float*)d_in[11];
  const float* W_out    = (const float*)d_in[12];
  const float* b_out    = (const float*)d_in[13];
  float* out = (float*)d_out;

  char* p = (char*)d_ws;
  u16* WPih = (u16*)p;       p += (size_t)4096 * 512 * 2;
  u16* WPhh = (u16*)p;       p += (size_t)4096 * 1024 * 2;
  float* biasP = (float*)p;  p += (size_t)4096 * 4;
  u16* Xall = (u16*)p;       p += (size_t)NSTEP * 256 * 512 * 2;
  u16* Hall = (u16*)p;       p += (size_t)32 * 256 * 1024 * 2;
  float* c0 = (float*)p;     p += (size_t)256 * 1024 * 4;
  float* psum = (float*)p;   p += (size_t)MROWS_ * NTV_ * 4;
  float* tlog = (float*)p;   p += (size_t)MROWS_ * 4;
  unsigned* syncbuf = (unsigned*)p; p += 256;
  u16* WoutB = (u16*)p;      p += (size_t)VOCAB_ * 1024 * 2;
  size_t woutEnd = (size_t)(p - (char*)d_ws);
  u16* featB = (u16*)p;      p += (size_t)256 * 2048 * 2;
  u16* WinitHB = (u16*)p;    p += (size_t)1024 * 2048 * 2;
  u16* WinitCB = (u16*)p;    p += (size_t)1024 * 2048 * 2;
  size_t initEnd = (size_t)(p - (char*)d_ws);

  bool haveWoutB = (ws_size >= woutEnd);
  bool haveInitB = (ws_size >= initEnd);

  float* accum = (float*)syncbuf;

  dim3 blk(256);
  zero_words_k<<<1, 64, 0, stream>>>(syncbuf);
  cvt_permute_k<<<4096, 128, 0, stream>>>(W_ih, W_hh, b_ih, b_hh, WPih, WPhh, biasP);
  gather_x_k<<<3968, blk, 0, stream>>>(emb, caption, Xall);
  if (haveWoutB) cvt_bf16_k<<<10000, blk, 0, stream>>>(W_out, WoutB, 2560000);

  if (haveInitB) {
    cvt_bf16_k<<<512, blk, 0, stream>>>(feature, featB, 131072);
    cvt_bf16_k<<<2048, blk, 0, stream>>>(W_init_h, WinitHB, 524288);
    cvt_bf16_k<<<2048, blk, 0, stream>>>(W_init_c, WinitCB, 524288);
    dim3 gi(16, 4);
    mfma_init_k<<<gi, blk, 0, stream>>>(featB, WinitHB, b_init_h, Hall, nullptr);
    mfma_init_k<<<gi, blk, 0, stream>>>(featB, WinitCB, b_init_c, nullptr, c0);
  } else {
    dim3 gi(16, 4);
    gemm_nt_bias_k<<<gi, blk, 0, stream>>>(feature, W_init_h, b_init_h, nullptr, Hall,
                                           BS_, MEM_, FEAT_);
    gemm_nt_bias_k<<<gi, blk, 0, stream>>>(feature, W_init_c, b_init_c, c0, nullptr,
                                           BS_, MEM_, FEAT_);
  }

  for (int t = 0; t < NSTEP; ++t) {
    lstm_step_k<<<256, blk, 0, stream>>>(Xall + (size_t)t * BS_ * EMB_,
                                         Hall + (size_t)t * BS_ * MEM_,
                                         Hall + (size_t)(t + 1) * BS_ * MEM_,
                                         WPih, WPhh, biasP, c0);
  }

  if (haveWoutB)
    mfma_logits_k<<<NTV_ * 62, blk, 0, stream>>>(Hall + (size_t)BS_ * MEM_, WoutB,
                                                 b_out, caption, psum, tlog);
  else
    mfma_logits_conv_k<<<NTV_ * 62, blk, 0, stream>>>(Hall + (size_t)BS_ * MEM_, W_out,
                                                      b_out, caption, psum, tlog);

  combine_k<<<31, blk, 0, stream>>>(psum, tlog, caption, accum);
  finalize_k<<<1, 1, 0, stream>>>(accum, out);
}